// Round 6
// baseline (1006.752 us; speedup 1.0000x reference)
//
#include <hip/hip_runtime.h>
#include <math.h>

#define NTOK 2048
#define NCH 16

// ---------------- compile-time G(3,0,1) tables ----------------
struct GEnt { unsigned char i, j, k; signed char s; };

constexpr int IDX2MASK[16] = {0,1,2,4,8,3,5,9,6,10,12,7,11,13,14,15};
constexpr int MASK2IDX[16] = {0,1,2,5,3,6,8,11,4,7,9,12,10,13,14,15};

constexpr int rsign(int a, int b){
  int cnt=0;
  for(int i=0;i<4;++i) if((b>>i)&1) for(int j=i+1;j<4;++j) if((a>>j)&1) cnt++;
  return (cnt&1)?-1:1;
}

struct GPTab { GEnt e[192]; };
constexpr GPTab make_gp(){
  GPTab t{}; int n=0;
  for(int ia=0; ia<16; ++ia) for(int ib=0; ib<16; ++ib){
    int a=IDX2MASK[ia], b=IDX2MASK[ib];
    if(a&b&1) continue;                      // e0^2 = 0
    t.e[n].i=(unsigned char)ia; t.e[n].j=(unsigned char)ib;
    t.e[n].k=(unsigned char)MASK2IDX[a^b]; t.e[n].s=(signed char)rsign(a,b);
    ++n;
  }
  return t;
}
static constexpr GPTab GP_TAB = make_gp();

struct JTab { GEnt e[81]; };
constexpr JTab make_join(){
  JTab t{}; int n=0;
  for(int ia=0; ia<16; ++ia) for(int ib=0; ib<16; ++ib){
    int a=IDX2MASK[ia], b=IDX2MASK[ib];
    if((a|b)!=15) continue;                  // dual supports must be disjoint
    int ca=(~a)&15, cb=(~b)&15, k=a&b, ck=(~k)&15;
    int s = rsign(a,ca)*rsign(b,cb)*rsign(ca,cb)*rsign(k,ck);
    t.e[n].i=(unsigned char)ia; t.e[n].j=(unsigned char)ib;
    t.e[n].k=(unsigned char)MASK2IDX[k]; t.e[n].s=(signed char)s;
    ++n;
  }
  return t;
}
static constexpr JTab J_TAB = make_join();

constexpr int INNER[8] = {0,2,3,4,8,9,10,14};   // blades without e0

__device__ __forceinline__ void apply_gp(float* o, const float* a, const float* b){
#pragma unroll
  for(int n=0;n<192;++n){
    const float s = (float)GP_TAB.e[n].s;
    o[GP_TAB.e[n].k] = fmaf(s*a[GP_TAB.e[n].i], b[GP_TAB.e[n].j], o[GP_TAB.e[n].k]);
  }
}
__device__ __forceinline__ void apply_join(float* o, const float* a, const float* b){
#pragma unroll
  for(int n=0;n<81;++n){
    const float s = (float)J_TAB.e[n].s;
    o[J_TAB.e[n].k] = fmaf(s*a[J_TAB.e[n].i], b[J_TAB.e[n].j], o[J_TAB.e[n].k]);
  }
}

// equi_linear for one output channel: 24 FMAs per input channel
// (16 grade-projection terms + 8 left-e0-multiplication terms)
__device__ __forceinline__ void elin_row(float acc[16], const float* xin, const float* w0p){
#pragma unroll
  for(int j=0;j<16;++j) acc[j]=0.0f;
#pragma unroll
  for(int i=0;i<16;++i){
    const float* w = w0p + i*9;
    const float4* xp = (const float4*)(xin + i*16);
    float4 A=xp[0], B=xp[1], Cc=xp[2], D=xp[3];
    float w0=w[0],w1=w[1],w2=w[2],w3=w[3],w4=w[4],w5=w[5],w6=w[6],w7=w[7],w8=w[8];
    acc[0] = fmaf(w0, A.x,  acc[0]);
    acc[1] = fmaf(w1, A.y,  acc[1]);
    acc[2] = fmaf(w1, A.z,  acc[2]);
    acc[3] = fmaf(w1, A.w,  acc[3]);
    acc[4] = fmaf(w1, B.x,  acc[4]);
    acc[5] = fmaf(w2, B.y,  acc[5]);
    acc[6] = fmaf(w2, B.z,  acc[6]);
    acc[7] = fmaf(w2, B.w,  acc[7]);
    acc[8] = fmaf(w2, Cc.x, acc[8]);
    acc[9] = fmaf(w2, Cc.y, acc[9]);
    acc[10]= fmaf(w2, Cc.z, acc[10]);
    acc[11]= fmaf(w3, Cc.w, acc[11]);
    acc[12]= fmaf(w3, D.x,  acc[12]);
    acc[13]= fmaf(w3, D.y,  acc[13]);
    acc[14]= fmaf(w3, D.z,  acc[14]);
    acc[15]= fmaf(w4, D.w,  acc[15]);
    // e0 left-multiplication maps
    acc[1] = fmaf(w5, A.x,  acc[1]);
    acc[5] = fmaf(w6, A.z,  acc[5]);
    acc[6] = fmaf(w6, A.w,  acc[6]);
    acc[7] = fmaf(w6, B.x,  acc[7]);
    acc[11]= fmaf(w7, Cc.x, acc[11]);
    acc[12]= fmaf(w7, Cc.y, acc[12]);
    acc[13]= fmaf(w7, Cc.z, acc[13]);
    acc[15]= fmaf(w8, D.z,  acc[15]);
  }
}

__device__ __forceinline__ float gelu_exact(float x){
  return 0.5f*x*(1.0f+erff(x*0.70710678118654752f));
}

#define WPAD 145          // weight o-stride pad: 145 mod 32 = 17, coprime with 32 -> no bank conflicts
#define TBS  264          // token buf stride (16*16 + 8): staggers token base banks
#define TPB  8            // tokens per workgroup (128 threads), grid 256 fills all CUs

// MODE 0: prologue (embed + W_in, then norm+QKV layer 0)
// MODE 1: Wo+res, norm, MLP(+res), norm, QKV for next layer
// MODE 2: Wo+res, norm, MLP(+res), W_out partial sum
template<int MODE>
__global__ __launch_bounds__(128) void token_kernel(
    const float* __restrict__ points, const float* __restrict__ Win,
    const float* __restrict__ Wo, const float* __restrict__ Wl,
    const float* __restrict__ Wr, const float* __restrict__ Wm,
    const float* __restrict__ Wq, const float* __restrict__ Wk,
    const float* __restrict__ Wv, const float* __restrict__ Wout,
    const float* __restrict__ ATT, float* __restrict__ X,
    float* __restrict__ Qg, float* __restrict__ Kg, float* __restrict__ Vg,
    float* __restrict__ toksum)
{
  __shared__ float wlds[6*16*WPAD];  // slots: 0 Wl, 1 Wr, 2 Wm, 3 Wq, 4 Wk, 5 Wv
  __shared__ float buf[TPB*TBS];
  __shared__ float sred[TPB*16];
  const int tid = threadIdx.x;
  const int t = tid>>4, o = tid&15;
  const int n = blockIdx.x*TPB + t;

  auto stage = [&](float* dst, const float* src){
#pragma unroll
    for(int r=0;r<18;++r){
      int k = tid + r*128;                    // 2304 = 18*128 exact
      dst[(k/144)*WPAD + (k%144)] = src[k];
    }
  };
  if (MODE==0){ stage(wlds+3*16*WPAD, Wq); stage(wlds+4*16*WPAD, Wk); stage(wlds+5*16*WPAD, Wv); }
  if (MODE==1){ stage(wlds+0*16*WPAD, Wl); stage(wlds+1*16*WPAD, Wr); stage(wlds+2*16*WPAD, Wm);
                stage(wlds+3*16*WPAD, Wq); stage(wlds+4*16*WPAD, Wk); stage(wlds+5*16*WPAD, Wv); }
  if (MODE==2){ stage(wlds+0*16*WPAD, Wl); stage(wlds+1*16*WPAD, Wr); stage(wlds+2*16*WPAD, Wm); }

  float* tb = buf + t*TBS;
  float xr[16];

  if (MODE==0){
    float px = points[n*3+0], py = points[n*3+1], pz = points[n*3+2];
    float w3 = Win[o*9+3], w8 = Win[o*9+8];
#pragma unroll
    for(int j=0;j<16;++j) xr[j]=0.0f;
    xr[11]= w3*pz; xr[12]= -w3*py; xr[13]= w3*px; xr[14]= w3; xr[15]= w8;
    float4* xg = (float4*)(X + (size_t)n*256 + o*16);
    xg[0]=make_float4(xr[0],xr[1],xr[2],xr[3]);
    xg[1]=make_float4(xr[4],xr[5],xr[6],xr[7]);
    xg[2]=make_float4(xr[8],xr[9],xr[10],xr[11]);
    xg[3]=make_float4(xr[12],xr[13],xr[14],xr[15]);
  } else {
    const float4* xg = (const float4*)(X + (size_t)n*256 + o*16);
    float4 a=xg[0],b=xg[1],c=xg[2],d=xg[3];
    xr[0]=a.x; xr[1]=a.y; xr[2]=a.z; xr[3]=a.w;
    xr[4]=b.x; xr[5]=b.y; xr[6]=b.z; xr[7]=b.w;
    xr[8]=c.x; xr[9]=c.y; xr[10]=c.z; xr[11]=c.w;
    xr[12]=d.x; xr[13]=d.y; xr[14]=d.z; xr[15]=d.w;
    const float4* ag = (const float4*)(ATT + (size_t)n*256 + o*16);
    float4* bp = (float4*)(tb + o*16);
    bp[0]=ag[0]; bp[1]=ag[1]; bp[2]=ag[2]; bp[3]=ag[3];
    __syncthreads();
    float acc[16];
    elin_row(acc, tb, Wo + o*144);            // Wo from global (L1/L2-hot)
#pragma unroll
    for(int j=0;j<16;++j) xr[j]+=acc[j];
    // --- norm 1 ---
    float s=0;
#pragma unroll
    for(int z=0;z<8;++z){ float v=xr[INNER[z]]; s=fmaf(v,v,s); }
    sred[tid]=s; __syncthreads();
    float tot=0;
#pragma unroll
    for(int c2=0;c2<16;++c2) tot += sred[t*16+c2];
    float f = 1.0f/sqrtf(tot*(1.0f/16.0f)+1e-6f);
    float4* bp2=(float4*)(tb+o*16);
    bp2[0]=make_float4(xr[0]*f,xr[1]*f,xr[2]*f,xr[3]*f);
    bp2[1]=make_float4(xr[4]*f,xr[5]*f,xr[6]*f,xr[7]*f);
    bp2[2]=make_float4(xr[8]*f,xr[9]*f,xr[10]*f,xr[11]*f);
    bp2[3]=make_float4(xr[12]*f,xr[13]*f,xr[14]*f,xr[15]*f);
    __syncthreads();
    // --- MLP ---
    float L[16], R[16];
    elin_row(L, tb, wlds+0*16*WPAD + o*WPAD);
    elin_row(R, tb, wlds+1*16*WPAD + o*WPAD);
    float h[16];
#pragma unroll
    for(int j=0;j<16;++j) h[j]=0.0f;
    if (o<8) apply_gp(h,L,R); else apply_join(h,L,R);
    float gel = gelu_exact(h[0]);
#pragma unroll
    for(int j=0;j<16;++j) h[j]*=gel;
    __syncthreads();                          // Wl/Wr reads of buf done
    float4* bp3=(float4*)(tb+o*16);
    bp3[0]=make_float4(h[0],h[1],h[2],h[3]);
    bp3[1]=make_float4(h[4],h[5],h[6],h[7]);
    bp3[2]=make_float4(h[8],h[9],h[10],h[11]);
    bp3[3]=make_float4(h[12],h[13],h[14],h[15]);
    __syncthreads();
    float mm2[16];
    elin_row(mm2, tb, wlds+2*16*WPAD + o*WPAD);
#pragma unroll
    for(int j=0;j<16;++j) xr[j]+=mm2[j];
    if (MODE==1){
      float4* xs = (float4*)(X + (size_t)n*256 + o*16);
      xs[0]=make_float4(xr[0],xr[1],xr[2],xr[3]);
      xs[1]=make_float4(xr[4],xr[5],xr[6],xr[7]);
      xs[2]=make_float4(xr[8],xr[9],xr[10],xr[11]);
      xs[3]=make_float4(xr[12],xr[13],xr[14],xr[15]);
    }
  }

  if (MODE==2){
    sred[tid] = Wout[o*9]*xr[0];              // only grade-0 weight reaches comp 0
    __syncthreads();
    if (o==0){
      float s2=0;
#pragma unroll
      for(int c2=0;c2<16;++c2) s2+=sred[t*16+c2];
      toksum[n]=s2;
    }
    return;
  }

  // --- norm 2 + QKV (MODE 0 and 1) ---
  {
    float s=0;
#pragma unroll
    for(int z=0;z<8;++z){ float v=xr[INNER[z]]; s=fmaf(v,v,s); }
    sred[tid]=s; __syncthreads();
    float tot=0;
#pragma unroll
    for(int c2=0;c2<16;++c2) tot += sred[t*16+c2];
    float f2 = 1.0f/sqrtf(tot*(1.0f/16.0f)+1e-6f);
    float4* bp4=(float4*)(tb+o*16);
    bp4[0]=make_float4(xr[0]*f2,xr[1]*f2,xr[2]*f2,xr[3]*f2);
    bp4[1]=make_float4(xr[4]*f2,xr[5]*f2,xr[6]*f2,xr[7]*f2);
    bp4[2]=make_float4(xr[8]*f2,xr[9]*f2,xr[10]*f2,xr[11]*f2);
    bp4[3]=make_float4(xr[12]*f2,xr[13]*f2,xr[14]*f2,xr[15]*f2);
    __syncthreads();
    float q_[16],k_[16],v_[16];
    elin_row(q_, tb, wlds+3*16*WPAD+o*WPAD);
    elin_row(k_, tb, wlds+4*16*WPAD+o*WPAD);
    elin_row(v_, tb, wlds+5*16*WPAD+o*WPAD);
    int hh=o>>1, cc=o&1;
    size_t qb = ((size_t)hh*NTOK + n)*16 + cc*8;
    *(float4*)(Qg+qb)   = make_float4(q_[0],q_[2],q_[3],q_[4]);
    *(float4*)(Qg+qb+4) = make_float4(q_[8],q_[9],q_[10],q_[14]);
    *(float4*)(Kg+qb)   = make_float4(k_[0],k_[2],k_[3],k_[4]);
    *(float4*)(Kg+qb+4) = make_float4(k_[8],k_[9],k_[10],k_[14]);
    size_t vb = ((size_t)hh*NTOK + n)*32 + cc*16;
    float4* vp=(float4*)(Vg+vb);
    vp[0]=make_float4(v_[0],v_[1],v_[2],v_[3]);
    vp[1]=make_float4(v_[4],v_[5],v_[6],v_[7]);
    vp[2]=make_float4(v_[8],v_[9],v_[10],v_[11]);
    vp[3]=make_float4(v_[12],v_[13],v_[14],v_[15]);
  }
}

// ---------------- attention: flash-style online softmax ----------------
// Grid 1024 = 8 heads x 128 q-blocks(16 q). Block 256 = 16 q (low nibble) x 16 key-splits.
// TS=128 keys/tile; split s owns keys {s+16u} (interleaved -> concurrent waves hit
// consecutive K rows = 2-way broadcast, free). V rows padded 32->36 floats so the 4
// concurrent V rows land on distinct bank groups. 4 blocks/CU -> 16 waves/CU (50%).
#define TSB 128
#define CSTR 35          // combine record stride (odd -> conflict-free: 35*tid mod 32 = 3*tid)
__global__ __launch_bounds__(256, 4) void attn_kernel(
    const float* __restrict__ Qg, const float* __restrict__ Kg,
    const float* __restrict__ Vg, float* __restrict__ ATT)
{
  __shared__ float smem[256*CSTR];            // 8960 floats = 35 KB; tiles (2048+4608=6656) fit inside
  float* Kl = smem;                            // [128][16]
  float* Vl = smem + TSB*16;                   // [128][36] padded rows
  const int tid = threadIdx.x;
  const int h  = blockIdx.x >> 7;
  const int qb = blockIdx.x & 127;
  const int q  = tid & 15;
  const int s  = tid >> 4;
  const int n  = qb*16 + q;

  float qv[16];
  {
    const float4* qp = (const float4*)(Qg + ((size_t)h*NTOK + n)*16);
    float4 q0=qp[0],q1=qp[1],q2=qp[2],q3=qp[3];
    qv[0]=q0.x*0.25f; qv[1]=q0.y*0.25f; qv[2]=q0.z*0.25f; qv[3]=q0.w*0.25f;
    qv[4]=q1.x*0.25f; qv[5]=q1.y*0.25f; qv[6]=q1.z*0.25f; qv[7]=q1.w*0.25f;
    qv[8]=q2.x*0.25f; qv[9]=q2.y*0.25f; qv[10]=q2.z*0.25f; qv[11]=q2.w*0.25f;
    qv[12]=q3.x*0.25f; qv[13]=q3.y*0.25f; qv[14]=q3.z*0.25f; qv[15]=q3.w*0.25f;
  }

  float m = -INFINITY, l = 0.0f;
  float acc[32];
#pragma unroll
  for(int z=0;z<32;++z) acc[z]=0.0f;

#pragma unroll 1
  for(int t0=0;t0<NTOK;t0+=TSB){
    __syncthreads();
    const float4* ksrc = (const float4*)(Kg + ((size_t)h*NTOK + t0)*16);
    float4* kdst = (float4*)Kl;                // 512 f4, 2/thread
    kdst[tid]     = ksrc[tid];
    kdst[tid+256] = ksrc[tid+256];
    const float4* vsrc = (const float4*)(Vg + ((size_t)h*NTOK + t0)*32);
    float4* vdst = (float4*)Vl;                // 1024 f4 into padded rows of 9 f4
#pragma unroll
    for(int r=0;r<4;++r){
      int g = tid + r*256;
      vdst[(g>>3)*9 + (g&7)] = vsrc[g];
    }
    __syncthreads();

    float d[8];
#pragma unroll
    for(int u=0;u<8;++u){
      const float4* kr = (const float4*)(Kl + (s+16*u)*16);
      float4 k0=kr[0], k1=kr[1], k2=kr[2], k3=kr[3];
      float dd;
      dd =      qv[0]*k0.x;
      dd = fmaf(qv[1],k0.y,dd); dd = fmaf(qv[2],k0.z,dd); dd = fmaf(qv[3],k0.w,dd);
      dd = fmaf(qv[4],k1.x,dd); dd = fmaf(qv[5],k1.y,dd); dd = fmaf(qv[6],k1.z,dd);
      dd = fmaf(qv[7],k1.w,dd); dd = fmaf(qv[8],k2.x,dd); dd = fmaf(qv[9],k2.y,dd);
      dd = fmaf(qv[10],k2.z,dd); dd = fmaf(qv[11],k2.w,dd); dd = fmaf(qv[12],k3.x,dd);
      dd = fmaf(qv[13],k3.y,dd); dd = fmaf(qv[14],k3.z,dd); dd = fmaf(qv[15],k3.w,dd);
      d[u]=dd;
    }
    float cmax = d[0];
#pragma unroll
    for(int u=1;u<8;++u) cmax = fmaxf(cmax, d[u]);
    if (cmax > m){
      float corr = __expf(m - cmax);
      m = cmax; l *= corr;
#pragma unroll
      for(int z=0;z<32;++z) acc[z]*=corr;
    }
#pragma unroll
    for(int u=0;u<8;++u){
      float p = __expf(d[u]-m);
      l += p;
      const float4* vr4 = (const float4*)(Vl + (s+16*u)*36);
#pragma unroll
      for(int zz=0;zz<8;++zz){
        float4 vv = vr4[zz];
        acc[zz*4+0] = fmaf(p, vv.x, acc[zz*4+0]);
        acc[zz*4+1] = fmaf(p, vv.y, acc[zz*4+1]);
        acc[zz*4+2] = fmaf(p, vv.z, acc[zz*4+2]);
        acc[zz*4+3] = fmaf(p, vv.w, acc[zz*4+3]);
      }
    }
  }
  __syncthreads();
  // combine 16 key-splits per query; split s owns output comps {2s, 2s+1}
  float* cb = smem + tid*CSTR;                 // == (s*16+q)*CSTR, stride 35 -> conflict-free
  cb[0]=m; cb[1]=l;
#pragma unroll
  for(int z=0;z<32;++z) cb[2+z]=acc[z];
  __syncthreads();
  float M=-INFINITY;
#pragma unroll
  for(int s2=0;s2<16;++s2) M = fmaxf(M, smem[(s2*16+q)*CSTR]);
  float Lt=0.0f, o0=0.0f, o1=0.0f;
#pragma unroll
  for(int s2=0;s2<16;++s2){
    const float* pr = smem + (s2*16+q)*CSTR;
    float ww = __expf(pr[0]-M);
    Lt = fmaf(pr[1], ww, Lt);
    o0 = fmaf(pr[2+s*2+0], ww, o0);
    o1 = fmaf(pr[2+s*2+1], ww, o1);
  }
  float inv = 1.0f/Lt;
  // comp c32 = 2s: sub-channel = s>>3, comp16 = (s&7)*2
  size_t ob = (size_t)n*256 + (size_t)(2*h + (s>>3))*16 + (s&7)*2;
  *(float2*)(ATT+ob) = make_float2(o0*inv, o1*inv);
}

__global__ __launch_bounds__(256) void reduce_kernel(const float* __restrict__ tok, float* __restrict__ out){
  int tid=threadIdx.x;
  float s=0;
  for(int i=tid;i<NTOK;i+=256) s+=tok[i];
#pragma unroll
  for(int off=32;off>0;off>>=1) s += __shfl_down(s,off);
  __shared__ float red[4];
  if((tid&63)==0) red[tid>>6]=s;
  __syncthreads();
  if(tid==0) out[0]=(red[0]+red[1]+red[2]+red[3])*(1.0f/2048.0f);
}

extern "C" void kernel_launch(void* const* d_in, const int* in_sizes, int n_in,
                              void* d_out, int out_size, void* d_ws, size_t ws_size,
                              hipStream_t stream){
  const float* points=(const float*)d_in[0];
  const float* Win=(const float*)d_in[1];
  const float* Wq=(const float*)d_in[2];
  const float* Wk=(const float*)d_in[3];
  const float* Wv=(const float*)d_in[4];
  const float* Wo=(const float*)d_in[5];
  const float* Wl=(const float*)d_in[6];
  const float* Wr=(const float*)d_in[7];
  const float* Wm=(const float*)d_in[8];
  const float* Wout=(const float*)d_in[9];
  float* ws=(float*)d_ws;
  float* X   = ws;
  float* ATT = ws + 524288;
  float* Qg  = ws + 1048576;
  float* Kg  = ws + 1310720;
  float* Vg  = ws + 1572864;
  float* tok = ws + 2097152;
  float* out=(float*)d_out;

  token_kernel<0><<<256,128,0,stream>>>(points,Win,nullptr,nullptr,nullptr,nullptr,
                                        Wq,Wk,Wv,nullptr,nullptr,X,Qg,Kg,Vg,nullptr);
  for(int l=0;l<10;++l){
    attn_kernel<<<1024,256,0,stream>>>(Qg,Kg,Vg,ATT);
    if(l<9){
      token_kernel<1><<<256,128,0,stream>>>(nullptr,nullptr,
          Wo+l*2304,Wl+l*2304,Wr+l*2304,Wm+l*2304,
          Wq+(l+1)*2304,Wk+(l+1)*2304,Wv+(l+1)*2304,nullptr,
          ATT,X,Qg,Kg,Vg,nullptr);
    } else {
      token_kernel<2><<<256,128,0,stream>>>(nullptr,nullptr,
          Wo+l*2304,Wl+l*2304,Wr+l*2304,Wm+l*2304,
          nullptr,nullptr,nullptr,Wout,
          ATT,X,nullptr,nullptr,nullptr,tok);
    }
  }
  reduce_kernel<<<1,256,0,stream>>>(tok,out);
}

// Round 7
// 692.476 us; speedup vs baseline: 1.4538x; 1.4538x over previous
//
#include <hip/hip_runtime.h>
#include <math.h>

#define NTOK 2048

typedef short short8v __attribute__((ext_vector_type(8)));
typedef short short4v __attribute__((ext_vector_type(4)));
typedef float f32x4 __attribute__((ext_vector_type(4)));

__device__ __forceinline__ unsigned short f2bf(float x){
  unsigned u = __float_as_uint(x);
  u += 0x7fff + ((u>>16)&1);           // round-to-nearest-even
  return (unsigned short)(u>>16);
}

// ---------------- compile-time G(3,0,1) tables ----------------
struct GEnt { unsigned char i, j, k; signed char s; };

constexpr int IDX2MASK[16] = {0,1,2,4,8,3,5,9,6,10,12,7,11,13,14,15};
constexpr int MASK2IDX[16] = {0,1,2,5,3,6,8,11,4,7,9,12,10,13,14,15};

constexpr int rsign(int a, int b){
  int cnt=0;
  for(int i=0;i<4;++i) if((b>>i)&1) for(int j=i+1;j<4;++j) if((a>>j)&1) cnt++;
  return (cnt&1)?-1:1;
}

struct GPTab { GEnt e[192]; };
constexpr GPTab make_gp(){
  GPTab t{}; int n=0;
  for(int ia=0; ia<16; ++ia) for(int ib=0; ib<16; ++ib){
    int a=IDX2MASK[ia], b=IDX2MASK[ib];
    if(a&b&1) continue;
    t.e[n].i=(unsigned char)ia; t.e[n].j=(unsigned char)ib;
    t.e[n].k=(unsigned char)MASK2IDX[a^b]; t.e[n].s=(signed char)rsign(a,b);
    ++n;
  }
  return t;
}
static constexpr GPTab GP_TAB = make_gp();

struct JTab { GEnt e[81]; };
constexpr JTab make_join(){
  JTab t{}; int n=0;
  for(int ia=0; ia<16; ++ia) for(int ib=0; ib<16; ++ib){
    int a=IDX2MASK[ia], b=IDX2MASK[ib];
    if((a|b)!=15) continue;
    int ca=(~a)&15, cb=(~b)&15, k=a&b, ck=(~k)&15;
    int s = rsign(a,ca)*rsign(b,cb)*rsign(ca,cb)*rsign(k,ck);
    t.e[n].i=(unsigned char)ia; t.e[n].j=(unsigned char)ib;
    t.e[n].k=(unsigned char)MASK2IDX[k]; t.e[n].s=(signed char)s;
    ++n;
  }
  return t;
}
static constexpr JTab J_TAB = make_join();

constexpr int INNER[8] = {0,2,3,4,8,9,10,14};

__device__ __forceinline__ void apply_gp(float* o, const float* a, const float* b){
#pragma unroll
  for(int n=0;n<192;++n){
    const float s = (float)GP_TAB.e[n].s;
    o[GP_TAB.e[n].k] = fmaf(s*a[GP_TAB.e[n].i], b[GP_TAB.e[n].j], o[GP_TAB.e[n].k]);
  }
}
__device__ __forceinline__ void apply_join(float* o, const float* a, const float* b){
#pragma unroll
  for(int n=0;n<81;++n){
    const float s = (float)J_TAB.e[n].s;
    o[J_TAB.e[n].k] = fmaf(s*a[J_TAB.e[n].i], b[J_TAB.e[n].j], o[J_TAB.e[n].k]);
  }
}

__device__ __forceinline__ void elin_row(float acc[16], const float* xin, const float* w0p){
#pragma unroll
  for(int j=0;j<16;++j) acc[j]=0.0f;
#pragma unroll
  for(int i=0;i<16;++i){
    const float* w = w0p + i*9;
    const float4* xp = (const float4*)(xin + i*16);
    float4 A=xp[0], B=xp[1], Cc=xp[2], D=xp[3];
    float w0=w[0],w1=w[1],w2=w[2],w3=w[3],w4=w[4],w5=w[5],w6=w[6],w7=w[7],w8=w[8];
    acc[0] = fmaf(w0, A.x,  acc[0]);
    acc[1] = fmaf(w1, A.y,  acc[1]);
    acc[2] = fmaf(w1, A.z,  acc[2]);
    acc[3] = fmaf(w1, A.w,  acc[3]);
    acc[4] = fmaf(w1, B.x,  acc[4]);
    acc[5] = fmaf(w2, B.y,  acc[5]);
    acc[6] = fmaf(w2, B.z,  acc[6]);
    acc[7] = fmaf(w2, B.w,  acc[7]);
    acc[8] = fmaf(w2, Cc.x, acc[8]);
    acc[9] = fmaf(w2, Cc.y, acc[9]);
    acc[10]= fmaf(w2, Cc.z, acc[10]);
    acc[11]= fmaf(w3, Cc.w, acc[11]);
    acc[12]= fmaf(w3, D.x,  acc[12]);
    acc[13]= fmaf(w3, D.y,  acc[13]);
    acc[14]= fmaf(w3, D.z,  acc[14]);
    acc[15]= fmaf(w4, D.w,  acc[15]);
    acc[1] = fmaf(w5, A.x,  acc[1]);
    acc[5] = fmaf(w6, A.z,  acc[5]);
    acc[6] = fmaf(w6, A.w,  acc[6]);
    acc[7] = fmaf(w6, B.x,  acc[7]);
    acc[11]= fmaf(w7, Cc.x, acc[11]);
    acc[12]= fmaf(w7, Cc.y, acc[12]);
    acc[13]= fmaf(w7, Cc.z, acc[13]);
    acc[15]= fmaf(w8, D.z,  acc[15]);
  }
}

__device__ __forceinline__ float gelu_exact(float x){
  return 0.5f*x*(1.0f+erff(x*0.70710678118654752f));
}

#define WPAD 145
#define TBS  264
#define TPB  8

// MODE 0: embed + W_in, norm + QKV(layer0). MODE 1: Wo+res, norm, MLP(+res), norm, QKV.
// MODE 2: Wo+res, norm, MLP(+res), W_out partial.
template<int MODE>
__global__ __launch_bounds__(128) void token_kernel(
    const float* __restrict__ points, const float* __restrict__ Win,
    const float* __restrict__ Wo, const float* __restrict__ Wl,
    const float* __restrict__ Wr, const float* __restrict__ Wm,
    const float* __restrict__ Wq, const float* __restrict__ Wk,
    const float* __restrict__ Wv, const float* __restrict__ Wout,
    const float* __restrict__ ATT, float* __restrict__ X,
    unsigned short* __restrict__ Qg16, unsigned short* __restrict__ Kg16,
    unsigned short* __restrict__ VgT, float* __restrict__ toksum)
{
  __shared__ float wlds[6*16*WPAD];
  __shared__ float buf[TPB*TBS];
  __shared__ float sred[TPB*16];
  const int tid = threadIdx.x;
  const int t = tid>>4, o = tid&15;
  const int n = blockIdx.x*TPB + t;

  auto stage = [&](float* dst, const float* src){
#pragma unroll
    for(int r=0;r<18;++r){
      int k = tid + r*128;
      dst[(k/144)*WPAD + (k%144)] = src[k];
    }
  };
  if (MODE==0){ stage(wlds+3*16*WPAD, Wq); stage(wlds+4*16*WPAD, Wk); stage(wlds+5*16*WPAD, Wv); }
  if (MODE==1){ stage(wlds+0*16*WPAD, Wl); stage(wlds+1*16*WPAD, Wr); stage(wlds+2*16*WPAD, Wm);
                stage(wlds+3*16*WPAD, Wq); stage(wlds+4*16*WPAD, Wk); stage(wlds+5*16*WPAD, Wv); }
  if (MODE==2){ stage(wlds+0*16*WPAD, Wl); stage(wlds+1*16*WPAD, Wr); stage(wlds+2*16*WPAD, Wm); }

  float* tb = buf + t*TBS;
  float xr[16];

  if (MODE==0){
    float px = points[n*3+0], py = points[n*3+1], pz = points[n*3+2];
    float w3 = Win[o*9+3], w8 = Win[o*9+8];
#pragma unroll
    for(int j=0;j<16;++j) xr[j]=0.0f;
    xr[11]= w3*pz; xr[12]= -w3*py; xr[13]= w3*px; xr[14]= w3; xr[15]= w8;
    float4* xg = (float4*)(X + (size_t)n*256 + o*16);
    xg[0]=make_float4(xr[0],xr[1],xr[2],xr[3]);
    xg[1]=make_float4(xr[4],xr[5],xr[6],xr[7]);
    xg[2]=make_float4(xr[8],xr[9],xr[10],xr[11]);
    xg[3]=make_float4(xr[12],xr[13],xr[14],xr[15]);
  } else {
    const float4* xg = (const float4*)(X + (size_t)n*256 + o*16);
    float4 a=xg[0],b=xg[1],c=xg[2],d=xg[3];
    xr[0]=a.x; xr[1]=a.y; xr[2]=a.z; xr[3]=a.w;
    xr[4]=b.x; xr[5]=b.y; xr[6]=b.z; xr[7]=b.w;
    xr[8]=c.x; xr[9]=c.y; xr[10]=c.z; xr[11]=c.w;
    xr[12]=d.x; xr[13]=d.y; xr[14]=d.z; xr[15]=d.w;
    const float4* ag = (const float4*)(ATT + (size_t)n*256 + o*16);
    float4* bp = (float4*)(tb + o*16);
    bp[0]=ag[0]; bp[1]=ag[1]; bp[2]=ag[2]; bp[3]=ag[3];
    __syncthreads();
    float acc[16];
    elin_row(acc, tb, Wo + o*144);
#pragma unroll
    for(int j=0;j<16;++j) xr[j]+=acc[j];
    float s=0;
#pragma unroll
    for(int z=0;z<8;++z){ float v=xr[INNER[z]]; s=fmaf(v,v,s); }
    sred[tid]=s; __syncthreads();
    float tot=0;
#pragma unroll
    for(int c2=0;c2<16;++c2) tot += sred[t*16+c2];
    float f = 1.0f/sqrtf(tot*(1.0f/16.0f)+1e-6f);
    float4* bp2=(float4*)(tb+o*16);
    bp2[0]=make_float4(xr[0]*f,xr[1]*f,xr[2]*f,xr[3]*f);
    bp2[1]=make_float4(xr[4]*f,xr[5]*f,xr[6]*f,xr[7]*f);
    bp2[2]=make_float4(xr[8]*f,xr[9]*f,xr[10]*f,xr[11]*f);
    bp2[3]=make_float4(xr[12]*f,xr[13]*f,xr[14]*f,xr[15]*f);
    __syncthreads();
    float L[16], R[16];
    elin_row(L, tb, wlds+0*16*WPAD + o*WPAD);
    elin_row(R, tb, wlds+1*16*WPAD + o*WPAD);
    float h[16];
#pragma unroll
    for(int j=0;j<16;++j) h[j]=0.0f;
    if (o<8) apply_gp(h,L,R); else apply_join(h,L,R);
    float gel = gelu_exact(h[0]);
#pragma unroll
    for(int j=0;j<16;++j) h[j]*=gel;
    __syncthreads();
    float4* bp3=(float4*)(tb+o*16);
    bp3[0]=make_float4(h[0],h[1],h[2],h[3]);
    bp3[1]=make_float4(h[4],h[5],h[6],h[7]);
    bp3[2]=make_float4(h[8],h[9],h[10],h[11]);
    bp3[3]=make_float4(h[12],h[13],h[14],h[15]);
    __syncthreads();
    float mm2[16];
    elin_row(mm2, tb, wlds+2*16*WPAD + o*WPAD);
#pragma unroll
    for(int j=0;j<16;++j) xr[j]+=mm2[j];
    if (MODE==1){
      float4* xs = (float4*)(X + (size_t)n*256 + o*16);
      xs[0]=make_float4(xr[0],xr[1],xr[2],xr[3]);
      xs[1]=make_float4(xr[4],xr[5],xr[6],xr[7]);
      xs[2]=make_float4(xr[8],xr[9],xr[10],xr[11]);
      xs[3]=make_float4(xr[12],xr[13],xr[14],xr[15]);
    }
  }

  if (MODE==2){
    sred[tid] = Wout[o*9]*xr[0];
    __syncthreads();
    if (o==0){
      float s2=0;
#pragma unroll
      for(int c2=0;c2<16;++c2) s2+=sred[t*16+c2];
      toksum[n]=s2;
    }
    return;
  }

  // ---- norm2 + QKV (bf16 outputs for MFMA attention) ----
  {
    float s=0;
#pragma unroll
    for(int z=0;z<8;++z){ float v=xr[INNER[z]]; s=fmaf(v,v,s); }
    sred[tid]=s; __syncthreads();
    float tot=0;
#pragma unroll
    for(int c2=0;c2<16;++c2) tot += sred[t*16+c2];
    float f2 = 1.0f/sqrtf(tot*(1.0f/16.0f)+1e-6f);
    float4* bp4=(float4*)(tb+o*16);
    bp4[0]=make_float4(xr[0]*f2,xr[1]*f2,xr[2]*f2,xr[3]*f2);
    bp4[1]=make_float4(xr[4]*f2,xr[5]*f2,xr[6]*f2,xr[7]*f2);
    bp4[2]=make_float4(xr[8]*f2,xr[9]*f2,xr[10]*f2,xr[11]*f2);
    bp4[3]=make_float4(xr[12]*f2,xr[13]*f2,xr[14]*f2,xr[15]*f2);
    __syncthreads();
    float q_[16],k_[16],v_[16];
    elin_row(q_, tb, wlds+3*16*WPAD+o*WPAD);
    elin_row(k_, tb, wlds+4*16*WPAD+o*WPAD);
    elin_row(v_, tb, wlds+5*16*WPAD+o*WPAD);
    int hh=o>>1, cc=o&1;
    {
      unsigned qw[4], kw[4];
#pragma unroll
      for(int j=0;j<4;++j){
        unsigned short a0=f2bf(q_[INNER[2*j]]*0.25f), a1=f2bf(q_[INNER[2*j+1]]*0.25f);
        unsigned short b0=f2bf(k_[INNER[2*j]]),       b1=f2bf(k_[INNER[2*j+1]]);
        qw[j] = (unsigned)a0 | ((unsigned)a1<<16);
        kw[j] = (unsigned)b0 | ((unsigned)b1<<16);
      }
      size_t rb = ((size_t)hh*NTOK + n)*16 + cc*8;
      *(uint4*)(Qg16 + rb) = make_uint4(qw[0],qw[1],qw[2],qw[3]);
      *(uint4*)(Kg16 + rb) = make_uint4(kw[0],kw[1],kw[2],kw[3]);
    }
    // V: bounce through LDS to write transposed bf16 VgT[h][32][n]
    __syncthreads();                     // all elin_row reads of tb done
    {
      float4* vb = (float4*)(tb + o*16);
      vb[0]=make_float4(v_[0],v_[1],v_[2],v_[3]);
      vb[1]=make_float4(v_[4],v_[5],v_[6],v_[7]);
      vb[2]=make_float4(v_[8],v_[9],v_[10],v_[11]);
      vb[3]=make_float4(v_[12],v_[13],v_[14],v_[15]);
    }
    __syncthreads();
#pragma unroll
    for(int pp=0;pp<2;++pp){
      int p  = tid + pp*128;             // 256 (h,v) rows / 128 threads
      int h2 = p>>5, v2 = p&31;
      int oc = 2*h2 + (v2>>4), c2 = v2&15;
      unsigned vw[4];
#pragma unroll
      for(int j=0;j<4;++j){
        unsigned short e0=f2bf(buf[(2*j  )*TBS + oc*16 + c2]);
        unsigned short e1=f2bf(buf[(2*j+1)*TBS + oc*16 + c2]);
        vw[j]=(unsigned)e0 | ((unsigned)e1<<16);
      }
      *(uint4*)(VgT + ((size_t)(h2*32+v2))*NTOK + (size_t)blockIdx.x*TPB) = make_uint4(vw[0],vw[1],vw[2],vw[3]);
    }
  }
}

// ---------------- MFMA flash attention ----------------
// Grid 1024 = 8 heads x 128 q-tiles(16 q). Block 256 = 4 waves = 4 key-splits of 512.
// mfma_f32_16x16x32_bf16; A/B frag: lane l elem j -> k=(l>>4)*4+(j&3)+16*(j>>2);
// C/D: col=lane&15, row=(lane>>4)*4+reg (m89). No LDS staging of K/V (L2-resident,
// 1.25 MB bf16); LDS only for P relayout (per-wave dbuf) + final 4-way combine.
__global__ __launch_bounds__(256) void attn_kernel(
    const unsigned short* __restrict__ Qg16, const unsigned short* __restrict__ Kg16,
    const unsigned short* __restrict__ VgT,  float* __restrict__ ATT)
{
  __shared__ unsigned short Pl[4][2][16*36];   // [wave][dbuf][q=16][k=32 pad 36]
  __shared__ float cmb[4*32*17];               // [wave][v=32][q pad 17]
  __shared__ float ml[4*16*2];                 // [wave][q]{m,l}
  const int tid = threadIdx.x;
  const int l   = tid & 63, w = tid >> 6;
  const int h   = blockIdx.x >> 7, qb = blockIdx.x & 127;
  const int l15 = l & 15, lg = l >> 4;

  const short4v z4 = {0,0,0,0};
  short8v qa;
  {
    const short4v* qp = (const short4v*)(Qg16 + ((size_t)(h*NTOK + qb*16 + l15))*16 + lg*4);
    qa = __builtin_shufflevector(*qp, z4, 0,1,2,3,4,5,6,7);   // j0..3 real comps, j4..7 zero-pad
  }

  f32x4 acc0 = {0,0,0,0}, acc1 = {0,0,0,0};
  float m[4]  = {-INFINITY,-INFINITY,-INFINITY,-INFINITY};
  float ls[4] = {0,0,0,0};
  const int key0 = w*512;

#pragma unroll 1
  for(int kc=0; kc<512; kc+=32){
    // ---- QK^T: two 16-key tiles ----
    f32x4 S[2];
#pragma unroll
    for(int t2=0;t2<2;++t2){
      const short4v* kp = (const short4v*)(Kg16 + ((size_t)(h*NTOK + key0 + kc + t2*16 + l15))*16 + lg*4);
      short8v kf = __builtin_shufflevector(*kp, z4, 0,1,2,3,4,5,6,7);
      f32x4 z = {0,0,0,0};
      S[t2] = __builtin_amdgcn_mfma_f32_16x16x32_bf16(qa, kf, z, 0,0,0);
    }
    // ---- online softmax (rows = q, spread over 16 lanes = keys) ----
    float corr[4];
#pragma unroll
    for(int r=0;r<4;++r){
      float mx = fmaxf(S[0][r], S[1][r]);
      mx = fmaxf(mx, __shfl_xor(mx, 1));
      mx = fmaxf(mx, __shfl_xor(mx, 2));
      mx = fmaxf(mx, __shfl_xor(mx, 4));
      mx = fmaxf(mx, __shfl_xor(mx, 8));
      float nm = fmaxf(m[r], mx);
      corr[r] = __expf(m[r] - nm);
      m[r] = nm;
    }
    float p0[4], p1[4];
#pragma unroll
    for(int r=0;r<4;++r){ p0[r] = __expf(S[0][r]-m[r]); p1[r] = __expf(S[1][r]-m[r]); }
#pragma unroll
    for(int r=0;r<4;++r){
      float s = p0[r] + p1[r];
      s += __shfl_xor(s, 1); s += __shfl_xor(s, 2);
      s += __shfl_xor(s, 4); s += __shfl_xor(s, 8);
      ls[r] = ls[r]*corr[r] + s;
      acc0[r] *= corr[r]; acc1[r] *= corr[r];
    }
    // ---- P -> LDS (bf16, relayout C-layout -> A-frag layout) ----
    unsigned short* Pc = &Pl[w][(kc>>5)&1][0];
#pragma unroll
    for(int r=0;r<4;++r){
      Pc[(lg*4+r)*36 +      l15] = f2bf(p0[r]);
      Pc[(lg*4+r)*36 + 16 + l15] = f2bf(p1[r]);
    }
    asm volatile("s_waitcnt lgkmcnt(0)" ::: "memory");
    __builtin_amdgcn_sched_barrier(0);
    // ---- PV ----
    const short4v* pr0 = (const short4v*)(Pc + l15*36 +      lg*4);
    const short4v* pr1 = (const short4v*)(Pc + l15*36 + 16 + lg*4);
    short8v pa = __builtin_shufflevector(*pr0, *pr1, 0,1,2,3,4,5,6,7);
    size_t vbase = ((size_t)(h*32 + l15))*NTOK + key0 + kc;
    const short4v* vr0a = (const short4v*)(VgT + vbase + lg*4);
    const short4v* vr0b = (const short4v*)(VgT + vbase + 16 + lg*4);
    short8v vb0 = __builtin_shufflevector(*vr0a, *vr0b, 0,1,2,3,4,5,6,7);
    size_t vbase1 = vbase + (size_t)16*NTOK;
    const short4v* vr1a = (const short4v*)(VgT + vbase1 + lg*4);
    const short4v* vr1b = (const short4v*)(VgT + vbase1 + 16 + lg*4);
    short8v vb1 = __builtin_shufflevector(*vr1a, *vr1b, 0,1,2,3,4,5,6,7);
    acc0 = __builtin_amdgcn_mfma_f32_16x16x32_bf16(pa, vb0, acc0, 0,0,0);
    acc1 = __builtin_amdgcn_mfma_f32_16x16x32_bf16(pa, vb1, acc1, 0,0,0);
  }

  // ---- 4-way key-split combine ----
  {
    float* cw = cmb + w*544;
#pragma unroll
    for(int r=0;r<4;++r){
      cw[ l15     *17 + lg*4 + r] = acc0[r];
      cw[(l15+16) *17 + lg*4 + r] = acc1[r];
    }
    if (l15 == 0){
#pragma unroll
      for(int r=0;r<4;++r){
        ml[(w*16 + lg*4 + r)*2]   = m[r];
        ml[(w*16 + lg*4 + r)*2+1] = ls[r];
      }
    }
  }
  __syncthreads();
  {
    int q = tid & 15, v = tid >> 4;       // v in 0..15; handles v and v+16
    float M = -INFINITY;
#pragma unroll
    for(int w2=0; w2<4; ++w2) M = fmaxf(M, ml[(w2*16+q)*2]);
    float L=0, a0=0, a1=0;
#pragma unroll
    for(int w2=0; w2<4; ++w2){
      float ww = __expf(ml[(w2*16+q)*2] - M);
      L  = fmaf(ml[(w2*16+q)*2+1], ww, L);
      a0 = fmaf(cmb[w2*544 +  v     *17 + q], ww, a0);
      a1 = fmaf(cmb[w2*544 + (v+16) *17 + q], ww, a1);
    }
    float inv = 1.0f/L;
    int n = qb*16 + q;
    ATT[(size_t)n*256 + (size_t)(2*h  )*16 + v] = a0*inv;
    ATT[(size_t)n*256 + (size_t)(2*h+1)*16 + v] = a1*inv;
  }
}

__global__ __launch_bounds__(256) void reduce_kernel(const float* __restrict__ tok, float* __restrict__ out){
  int tid=threadIdx.x;
  float s=0;
  for(int i=tid;i<NTOK;i+=256) s+=tok[i];
#pragma unroll
  for(int off=32;off>0;off>>=1) s += __shfl_down(s,off);
  __shared__ float red[4];
  if((tid&63)==0) red[tid>>6]=s;
  __syncthreads();
  if(tid==0) out[0]=(red[0]+red[1]+red[2]+red[3])*(1.0f/2048.0f);
}

extern "C" void kernel_launch(void* const* d_in, const int* in_sizes, int n_in,
                              void* d_out, int out_size, void* d_ws, size_t ws_size,
                              hipStream_t stream){
  const float* points=(const float*)d_in[0];
  const float* Win=(const float*)d_in[1];
  const float* Wq=(const float*)d_in[2];
  const float* Wk=(const float*)d_in[3];
  const float* Wv=(const float*)d_in[4];
  const float* Wo=(const float*)d_in[5];
  const float* Wl=(const float*)d_in[6];
  const float* Wr=(const float*)d_in[7];
  const float* Wm=(const float*)d_in[8];
  const float* Wout=(const float*)d_in[9];
  float* ws=(float*)d_ws;
  float* X    = ws;                                  // 524288 f
  float* ATT  = ws + 524288;                         // 524288 f
  unsigned short* Qg16 = (unsigned short*)(ws + 1048576);   // 262144 us
  unsigned short* Kg16 = (unsigned short*)(ws + 1179648);   // 262144 us
  unsigned short* VgT  = (unsigned short*)(ws + 1310720);   // 524288 us
  float* tok  = ws + 1572864;
  float* out=(float*)d_out;

  token_kernel<0><<<256,128,0,stream>>>(points,Win,nullptr,nullptr,nullptr,nullptr,
                                        Wq,Wk,Wv,nullptr,nullptr,X,Qg16,Kg16,VgT,nullptr);
  for(int l=0;l<10;++l){
    attn_kernel<<<1024,256,0,stream>>>(Qg16,Kg16,VgT,ATT);
    if(l<9){
      token_kernel<1><<<256,128,0,stream>>>(nullptr,nullptr,
          Wo+l*2304,Wl+l*2304,Wr+l*2304,Wm+l*2304,
          Wq+(l+1)*2304,Wk+(l+1)*2304,Wv+(l+1)*2304,nullptr,
          ATT,X,Qg16,Kg16,VgT,nullptr);
    } else {
      token_kernel<2><<<256,128,0,stream>>>(nullptr,nullptr,
          Wo+l*2304,Wl+l*2304,Wr+l*2304,Wm+l*2304,
          nullptr,nullptr,nullptr,Wout,
          ATT,X,nullptr,nullptr,nullptr,tok);
    }
  }
  reduce_kernel<<<1,256,0,stream>>>(tok,out);
}

// Round 9
// 664.435 us; speedup vs baseline: 1.5152x; 1.0422x over previous
//
#include <hip/hip_runtime.h>
#include <hip/hip_bf16.h>
#include <math.h>

#define NTOK 2048

typedef short short8v __attribute__((ext_vector_type(8)));
typedef short short4v __attribute__((ext_vector_type(4)));
typedef float f32x4 __attribute__((ext_vector_type(4)));
typedef unsigned u32x4 __attribute__((ext_vector_type(4)));

__device__ __forceinline__ unsigned short f2bf(float x){
  unsigned u = __float_as_uint(x);
  u += 0x7fff + ((u>>16)&1);           // round-to-nearest-even
  return (unsigned short)(u>>16);
}
__device__ __forceinline__ unsigned pack_bf2(float a, float b){
  __hip_bfloat162 h = __float22bfloat162_rn(float2{a,b});   // x -> low 16, y -> high 16
  return *reinterpret_cast<unsigned*>(&h);
}

// ---------------- compile-time G(3,0,1) tables ----------------
struct GEnt { unsigned char i, j, k; signed char s; };

constexpr int IDX2MASK[16] = {0,1,2,4,8,3,5,9,6,10,12,7,11,13,14,15};
constexpr int MASK2IDX[16] = {0,1,2,5,3,6,8,11,4,7,9,12,10,13,14,15};

constexpr int rsign(int a, int b){
  int cnt=0;
  for(int i=0;i<4;++i) if((b>>i)&1) for(int j=i+1;j<4;++j) if((a>>j)&1) cnt++;
  return (cnt&1)?-1:1;
}

struct GPTab { GEnt e[192]; };
constexpr GPTab make_gp(){
  GPTab t{}; int n=0;
  for(int ia=0; ia<16; ++ia) for(int ib=0; ib<16; ++ib){
    int a=IDX2MASK[ia], b=IDX2MASK[ib];
    if(a&b&1) continue;
    t.e[n].i=(unsigned char)ia; t.e[n].j=(unsigned char)ib;
    t.e[n].k=(unsigned char)MASK2IDX[a^b]; t.e[n].s=(signed char)rsign(a,b);
    ++n;
  }
  return t;
}
static constexpr GPTab GP_TAB = make_gp();

struct JTab { GEnt e[81]; };
constexpr JTab make_join(){
  JTab t{}; int n=0;
  for(int ia=0; ia<16; ++ia) for(int ib=0; ib<16; ++ib){
    int a=IDX2MASK[ia], b=IDX2MASK[ib];
    if((a|b)!=15) continue;
    int ca=(~a)&15, cb=(~b)&15, k=a&b, ck=(~k)&15;
    int s = rsign(a,ca)*rsign(b,cb)*rsign(ca,cb)*rsign(k,ck);
    t.e[n].i=(unsigned char)ia; t.e[n].j=(unsigned char)ib;
    t.e[n].k=(unsigned char)MASK2IDX[k]; t.e[n].s=(signed char)s;
    ++n;
  }
  return t;
}
static constexpr JTab J_TAB = make_join();

constexpr int INNER[8] = {0,2,3,4,8,9,10,14};

__device__ __forceinline__ void apply_gp(float* o, const float* a, const float* b){
#pragma unroll
  for(int n=0;n<192;++n){
    const float s = (float)GP_TAB.e[n].s;
    o[GP_TAB.e[n].k] = fmaf(s*a[GP_TAB.e[n].i], b[GP_TAB.e[n].j], o[GP_TAB.e[n].k]);
  }
}
__device__ __forceinline__ void apply_join(float* o, const float* a, const float* b){
#pragma unroll
  for(int n=0;n<81;++n){
    const float s = (float)J_TAB.e[n].s;
    o[J_TAB.e[n].k] = fmaf(s*a[J_TAB.e[n].i], b[J_TAB.e[n].j], o[J_TAB.e[n].k]);
  }
}

__device__ __forceinline__ void elin_row(float acc[16], const float* xin, const float* w0p){
#pragma unroll
  for(int j=0;j<16;++j) acc[j]=0.0f;
#pragma unroll
  for(int i=0;i<16;++i){
    const float* w = w0p + i*9;
    const float4* xp = (const float4*)(xin + i*16);
    float4 A=xp[0], B=xp[1], Cc=xp[2], D=xp[3];
    float w0=w[0],w1=w[1],w2=w[2],w3=w[3],w4=w[4],w5=w[5],w6=w[6],w7=w[7],w8=w[8];
    acc[0] = fmaf(w0, A.x,  acc[0]);
    acc[1] = fmaf(w1, A.y,  acc[1]);
    acc[2] = fmaf(w1, A.z,  acc[2]);
    acc[3] = fmaf(w1, A.w,  acc[3]);
    acc[4] = fmaf(w1, B.x,  acc[4]);
    acc[5] = fmaf(w2, B.y,  acc[5]);
    acc[6] = fmaf(w2, B.z,  acc[6]);
    acc[7] = fmaf(w2, B.w,  acc[7]);
    acc[8] = fmaf(w2, Cc.x, acc[8]);
    acc[9] = fmaf(w2, Cc.y, acc[9]);
    acc[10]= fmaf(w2, Cc.z, acc[10]);
    acc[11]= fmaf(w3, Cc.w, acc[11]);
    acc[12]= fmaf(w3, D.x,  acc[12]);
    acc[13]= fmaf(w3, D.y,  acc[13]);
    acc[14]= fmaf(w3, D.z,  acc[14]);
    acc[15]= fmaf(w4, D.w,  acc[15]);
    acc[1] = fmaf(w5, A.x,  acc[1]);
    acc[5] = fmaf(w6, A.z,  acc[5]);
    acc[6] = fmaf(w6, A.w,  acc[6]);
    acc[7] = fmaf(w6, B.x,  acc[7]);
    acc[11]= fmaf(w7, Cc.x, acc[11]);
    acc[12]= fmaf(w7, Cc.y, acc[12]);
    acc[13]= fmaf(w7, Cc.z, acc[13]);
    acc[15]= fmaf(w8, D.z,  acc[15]);
  }
}

__device__ __forceinline__ float gelu_exact(float x){
  return 0.5f*x*(1.0f+erff(x*0.70710678118654752f));
}

#define WPAD 145
#define TBS  264
#define TPB  8

// MODE 0: embed + W_in, norm + QKV(layer0). MODE 1: Wo+res, norm, MLP(+res), norm, QKV.
// MODE 2: Wo+res, norm, MLP(+res), W_out partial.
template<int MODE>
__global__ __launch_bounds__(128) void token_kernel(
    const float* __restrict__ points, const float* __restrict__ Win,
    const float* __restrict__ Wo, const float* __restrict__ Wl,
    const float* __restrict__ Wr, const float* __restrict__ Wm,
    const float* __restrict__ Wq, const float* __restrict__ Wk,
    const float* __restrict__ Wv, const float* __restrict__ Wout,
    const float* __restrict__ ATT, float* __restrict__ X,
    unsigned short* __restrict__ Qg16, unsigned short* __restrict__ Kg16,
    unsigned short* __restrict__ VgT, float* __restrict__ toksum)
{
  __shared__ float wlds[6*16*WPAD];
  __shared__ float buf[TPB*TBS];
  __shared__ float sred[TPB*16];
  const int tid = threadIdx.x;
  const int t = tid>>4, o = tid&15;
  const int n = blockIdx.x*TPB + t;

  auto stage = [&](float* dst, const float* src){
#pragma unroll
    for(int r=0;r<18;++r){
      int k = tid + r*128;
      dst[(k/144)*WPAD + (k%144)] = src[k];
    }
  };
  if (MODE==0){ stage(wlds+3*16*WPAD, Wq); stage(wlds+4*16*WPAD, Wk); stage(wlds+5*16*WPAD, Wv); }
  if (MODE==1){ stage(wlds+0*16*WPAD, Wl); stage(wlds+1*16*WPAD, Wr); stage(wlds+2*16*WPAD, Wm);
                stage(wlds+3*16*WPAD, Wq); stage(wlds+4*16*WPAD, Wk); stage(wlds+5*16*WPAD, Wv); }
  if (MODE==2){ stage(wlds+0*16*WPAD, Wl); stage(wlds+1*16*WPAD, Wr); stage(wlds+2*16*WPAD, Wm); }

  float* tb = buf + t*TBS;
  float xr[16];

  if (MODE==0){
    float px = points[n*3+0], py = points[n*3+1], pz = points[n*3+2];
    float w3 = Win[o*9+3], w8 = Win[o*9+8];
#pragma unroll
    for(int j=0;j<16;++j) xr[j]=0.0f;
    xr[11]= w3*pz; xr[12]= -w3*py; xr[13]= w3*px; xr[14]= w3; xr[15]= w8;
    float4* xg = (float4*)(X + (size_t)n*256 + o*16);
    xg[0]=make_float4(xr[0],xr[1],xr[2],xr[3]);
    xg[1]=make_float4(xr[4],xr[5],xr[6],xr[7]);
    xg[2]=make_float4(xr[8],xr[9],xr[10],xr[11]);
    xg[3]=make_float4(xr[12],xr[13],xr[14],xr[15]);
  } else {
    const float4* xg = (const float4*)(X + (size_t)n*256 + o*16);
    float4 a=xg[0],b=xg[1],c=xg[2],d=xg[3];
    xr[0]=a.x; xr[1]=a.y; xr[2]=a.z; xr[3]=a.w;
    xr[4]=b.x; xr[5]=b.y; xr[6]=b.z; xr[7]=b.w;
    xr[8]=c.x; xr[9]=c.y; xr[10]=c.z; xr[11]=c.w;
    xr[12]=d.x; xr[13]=d.y; xr[14]=d.z; xr[15]=d.w;
    const float4* ag = (const float4*)(ATT + (size_t)n*256 + o*16);
    float4* bp = (float4*)(tb + o*16);
    bp[0]=ag[0]; bp[1]=ag[1]; bp[2]=ag[2]; bp[3]=ag[3];
    __syncthreads();
    float acc[16];
    elin_row(acc, tb, Wo + o*144);
#pragma unroll
    for(int j=0;j<16;++j) xr[j]+=acc[j];
    float s=0;
#pragma unroll
    for(int z=0;z<8;++z){ float v=xr[INNER[z]]; s=fmaf(v,v,s); }
    sred[tid]=s; __syncthreads();
    float tot=0;
#pragma unroll
    for(int c2=0;c2<16;++c2) tot += sred[t*16+c2];
    float f = 1.0f/sqrtf(tot*(1.0f/16.0f)+1e-6f);
    float4* bp2=(float4*)(tb+o*16);
    bp2[0]=make_float4(xr[0]*f,xr[1]*f,xr[2]*f,xr[3]*f);
    bp2[1]=make_float4(xr[4]*f,xr[5]*f,xr[6]*f,xr[7]*f);
    bp2[2]=make_float4(xr[8]*f,xr[9]*f,xr[10]*f,xr[11]*f);
    bp2[3]=make_float4(xr[12]*f,xr[13]*f,xr[14]*f,xr[15]*f);
    __syncthreads();
    float L[16], R[16];
    elin_row(L, tb, wlds+0*16*WPAD + o*WPAD);
    elin_row(R, tb, wlds+1*16*WPAD + o*WPAD);
    float h[16];
#pragma unroll
    for(int j=0;j<16;++j) h[j]=0.0f;
    if (o<8) apply_gp(h,L,R); else apply_join(h,L,R);
    float gel = gelu_exact(h[0]);
#pragma unroll
    for(int j=0;j<16;++j) h[j]*=gel;
    __syncthreads();
    float4* bp3=(float4*)(tb+o*16);
    bp3[0]=make_float4(h[0],h[1],h[2],h[3]);
    bp3[1]=make_float4(h[4],h[5],h[6],h[7]);
    bp3[2]=make_float4(h[8],h[9],h[10],h[11]);
    bp3[3]=make_float4(h[12],h[13],h[14],h[15]);
    __syncthreads();
    float mm2[16];
    elin_row(mm2, tb, wlds+2*16*WPAD + o*WPAD);
#pragma unroll
    for(int j=0;j<16;++j) xr[j]+=mm2[j];
    if (MODE==1){
      float4* xs = (float4*)(X + (size_t)n*256 + o*16);
      xs[0]=make_float4(xr[0],xr[1],xr[2],xr[3]);
      xs[1]=make_float4(xr[4],xr[5],xr[6],xr[7]);
      xs[2]=make_float4(xr[8],xr[9],xr[10],xr[11]);
      xs[3]=make_float4(xr[12],xr[13],xr[14],xr[15]);
    }
  }

  if (MODE==2){
    sred[tid] = Wout[o*9]*xr[0];
    __syncthreads();
    if (o==0){
      float s2=0;
#pragma unroll
      for(int c2=0;c2<16;++c2) s2+=sred[t*16+c2];
      toksum[n]=s2;
    }
    return;
  }

  // ---- norm2 + QKV (bf16 outputs for MFMA attention) ----
  {
    float s=0;
#pragma unroll
    for(int z=0;z<8;++z){ float v=xr[INNER[z]]; s=fmaf(v,v,s); }
    sred[tid]=s; __syncthreads();
    float tot=0;
#pragma unroll
    for(int c2=0;c2<16;++c2) tot += sred[t*16+c2];
    float f2 = 1.0f/sqrtf(tot*(1.0f/16.0f)+1e-6f);
    float4* bp4=(float4*)(tb+o*16);
    bp4[0]=make_float4(xr[0]*f2,xr[1]*f2,xr[2]*f2,xr[3]*f2);
    bp4[1]=make_float4(xr[4]*f2,xr[5]*f2,xr[6]*f2,xr[7]*f2);
    bp4[2]=make_float4(xr[8]*f2,xr[9]*f2,xr[10]*f2,xr[11]*f2);
    bp4[3]=make_float4(xr[12]*f2,xr[13]*f2,xr[14]*f2,xr[15]*f2);
    __syncthreads();
    float q_[16],k_[16],v_[16];
    elin_row(q_, tb, wlds+3*16*WPAD+o*WPAD);
    elin_row(k_, tb, wlds+4*16*WPAD+o*WPAD);
    elin_row(v_, tb, wlds+5*16*WPAD+o*WPAD);
    int hh=o>>1, cc=o&1;
    {
      unsigned qw[4], kw[4];
#pragma unroll
      for(int j=0;j<4;++j){
        unsigned short a0=f2bf(q_[INNER[2*j]]*0.25f), a1=f2bf(q_[INNER[2*j+1]]*0.25f);
        unsigned short b0=f2bf(k_[INNER[2*j]]),       b1=f2bf(k_[INNER[2*j+1]]);
        qw[j] = (unsigned)a0 | ((unsigned)a1<<16);
        kw[j] = (unsigned)b0 | ((unsigned)b1<<16);
      }
      size_t rb = ((size_t)hh*NTOK + n)*16 + cc*8;
      *(uint4*)(Qg16 + rb) = make_uint4(qw[0],qw[1],qw[2],qw[3]);
      *(uint4*)(Kg16 + rb) = make_uint4(kw[0],kw[1],kw[2],kw[3]);
    }
    // V: bounce through LDS to write transposed bf16 VgT[h][32][n]
    __syncthreads();                     // all elin_row reads of tb done
    {
      float4* vb = (float4*)(tb + o*16);
      vb[0]=make_float4(v_[0],v_[1],v_[2],v_[3]);
      vb[1]=make_float4(v_[4],v_[5],v_[6],v_[7]);
      vb[2]=make_float4(v_[8],v_[9],v_[10],v_[11]);
      vb[3]=make_float4(v_[12],v_[13],v_[14],v_[15]);
    }
    __syncthreads();
#pragma unroll
    for(int pp=0;pp<2;++pp){
      int p  = tid + pp*128;             // 256 (h,v) rows / 128 threads
      int h2 = p>>5, v2 = p&31;
      int oc = 2*h2 + (v2>>4), c2 = v2&15;
      unsigned vw[4];
#pragma unroll
      for(int j=0;j<4;++j){
        unsigned short e0=f2bf(buf[(2*j  )*TBS + oc*16 + c2]);
        unsigned short e1=f2bf(buf[(2*j+1)*TBS + oc*16 + c2]);
        vw[j]=(unsigned)e0 | ((unsigned)e1<<16);
      }
      *(uint4*)(VgT + ((size_t)(h2*32+v2))*NTOK + (size_t)blockIdx.x*TPB) = make_uint4(vw[0],vw[1],vw[2],vw[3]);
    }
  }
}

// ---------------- MFMA flash attention, swapped QK^T ----------------
// Grid 1024 = 8 heads x 128 q-tiles(16 q). Block 256 = 4 waves = 4 key-splits of 512.
// S = mfma(K, Q): D[key][q] -> per lane (q=l15) keys live in regs; softmax is
// 15 in-reg fmax + 2 shfl; P lands EXACTLY in PV A-frag layout (pa[j]=p[j>>2][j&3])
// -> no LDS, no barriers in the main loop. acc[r] = O[q=lg*4+r][v=l15]; per-q corr
// reaches acc rows via 4 shfl broadcasts. Epilogue combine unchanged (validated r7).
__global__ __launch_bounds__(256) void attn_kernel(
    const unsigned short* __restrict__ Qg16, const unsigned short* __restrict__ Kg16,
    const unsigned short* __restrict__ VgT,  float* __restrict__ ATT)
{
  __shared__ float cmb[4*32*17];               // [wave][v=32][q pad 17]
  __shared__ float ml[4*16*2];                 // [wave][q]{m,l}
  const int tid = threadIdx.x;
  const int l   = tid & 63, w = tid >> 6;
  const int h   = blockIdx.x >> 7, qb = blockIdx.x & 127;
  const int l15 = l & 15, lg = l >> 4;

  const short4v z4 = {0,0,0,0};
  short8v qf;                                   // B-operand: row=q=l15
  {
    const short4v* qp = (const short4v*)(Qg16 + ((size_t)(h*NTOK + qb*16 + l15))*16 + lg*4);
    qf = __builtin_shufflevector(*qp, z4, 0,1,2,3,4,5,6,7);
  }

  f32x4 acc0 = {0,0,0,0}, acc1 = {0,0,0,0};    // O[q=lg*4+r][v=l15], v+16
  float m = -INFINITY, ls = 0.0f;              // softmax state for q=l15
  const int key0 = w*512;
  const size_t vrow = ((size_t)(h*32 + l15))*NTOK;

#pragma unroll 2
  for(int kc=0; kc<512; kc+=64){
    // ---- QK^T: 4 tiles of 16 keys; S[t][r] = S[key=key0+kc+16t+lg*4+r][q=l15]
    f32x4 S[4];
#pragma unroll
    for(int t2=0;t2<4;++t2){
      const short4v* kp = (const short4v*)(Kg16 + ((size_t)(h*NTOK + key0 + kc + t2*16 + l15))*16 + lg*4);
      short8v kf = __builtin_shufflevector(*kp, z4, 0,1,2,3,4,5,6,7);
      f32x4 z = {0,0,0,0};
      S[t2] = __builtin_amdgcn_mfma_f32_16x16x32_bf16(kf, qf, z, 0,0,0);
    }
    // ---- online softmax over 16 in-reg keys + 2 shfl (lanes sharing q=l15) ----
    float mx = S[0][0];
#pragma unroll
    for(int t2=0;t2<4;++t2)
#pragma unroll
      for(int r=0;r<4;++r) mx = fmaxf(mx, S[t2][r]);
    mx = fmaxf(mx, __shfl_xor(mx, 16));
    mx = fmaxf(mx, __shfl_xor(mx, 32));
    float nm = fmaxf(m, mx);
    float corr = __expf(m - nm);
    m = nm;
    float p[4][4];
    float s = 0.0f;
#pragma unroll
    for(int t2=0;t2<4;++t2)
#pragma unroll
      for(int r=0;r<4;++r){ float pv = __expf(S[t2][r]-nm); p[t2][r]=pv; s += pv; }
    s += __shfl_xor(s, 16);
    s += __shfl_xor(s, 32);
    ls = ls*corr + s;
    // ---- rescale acc rows (q=lg*4+r) by that q's corr ----
    float c0 = __shfl(corr, lg*4+0);
    float c1 = __shfl(corr, lg*4+1);
    float c2 = __shfl(corr, lg*4+2);
    float c3 = __shfl(corr, lg*4+3);
    acc0[0]*=c0; acc0[1]*=c1; acc0[2]*=c2; acc0[3]*=c3;
    acc1[0]*=c0; acc1[1]*=c1; acc1[2]*=c2; acc1[3]*=c3;
    // ---- P already in A-frag layout: pa[j]=p[j>>2][j&3] (keys 0-31), pa2: 32-63 ----
    u32x4 paw, paw2;
    paw[0]=pack_bf2(p[0][0],p[0][1]); paw[1]=pack_bf2(p[0][2],p[0][3]);
    paw[2]=pack_bf2(p[1][0],p[1][1]); paw[3]=pack_bf2(p[1][2],p[1][3]);
    paw2[0]=pack_bf2(p[2][0],p[2][1]); paw2[1]=pack_bf2(p[2][2],p[2][3]);
    paw2[2]=pack_bf2(p[3][0],p[3][1]); paw2[3]=pack_bf2(p[3][2],p[3][3]);
    short8v pa  = *reinterpret_cast<short8v*>(&paw);
    short8v pa2 = *reinterpret_cast<short8v*>(&paw2);
    // ---- PV: B rows = v-comps (l15 / l15+16), k along keys ----
    size_t vb = vrow + key0 + kc;
    const short4v* v0a = (const short4v*)(VgT + vb + lg*4);
    const short4v* v0b = (const short4v*)(VgT + vb + 16 + lg*4);
    const short4v* v0c = (const short4v*)(VgT + vb + 32 + lg*4);
    const short4v* v0d = (const short4v*)(VgT + vb + 48 + lg*4);
    short8v vb0  = __builtin_shufflevector(*v0a, *v0b, 0,1,2,3,4,5,6,7);
    short8v vb0b = __builtin_shufflevector(*v0c, *v0d, 0,1,2,3,4,5,6,7);
    size_t vb1s = vb + (size_t)16*NTOK;
    const short4v* v1a = (const short4v*)(VgT + vb1s + lg*4);
    const short4v* v1b = (const short4v*)(VgT + vb1s + 16 + lg*4);
    const short4v* v1c = (const short4v*)(VgT + vb1s + 32 + lg*4);
    const short4v* v1d = (const short4v*)(VgT + vb1s + 48 + lg*4);
    short8v vb1  = __builtin_shufflevector(*v1a, *v1b, 0,1,2,3,4,5,6,7);
    short8v vb1b = __builtin_shufflevector(*v1c, *v1d, 0,1,2,3,4,5,6,7);
    acc0 = __builtin_amdgcn_mfma_f32_16x16x32_bf16(pa,  vb0,  acc0, 0,0,0);
    acc0 = __builtin_amdgcn_mfma_f32_16x16x32_bf16(pa2, vb0b, acc0, 0,0,0);
    acc1 = __builtin_amdgcn_mfma_f32_16x16x32_bf16(pa,  vb1,  acc1, 0,0,0);
    acc1 = __builtin_amdgcn_mfma_f32_16x16x32_bf16(pa2, vb1b, acc1, 0,0,0);
  }

  // ---- 4-way key-split combine ----
  {
    float* cw = cmb + w*544;
#pragma unroll
    for(int r=0;r<4;++r){
      cw[ l15     *17 + lg*4 + r] = acc0[r];
      cw[(l15+16) *17 + lg*4 + r] = acc1[r];
    }
    if (lg == 0){
      ml[(w*16 + l15)*2]   = m;
      ml[(w*16 + l15)*2+1] = ls;
    }
  }
  __syncthreads();
  {
    int q = tid & 15, v = tid >> 4;       // v in 0..15; handles v and v+16
    float M = -INFINITY;
#pragma unroll
    for(int w2=0; w2<4; ++w2) M = fmaxf(M, ml[(w2*16+q)*2]);
    float L=0, a0=0, a1=0;
#pragma unroll
    for(int w2=0; w2<4; ++w2){
      float ww = __expf(ml[(w2*16+q)*2] - M);
      L  = fmaf(ml[(w2*16+q)*2+1], ww, L);
      a0 = fmaf(cmb[w2*544 +  v     *17 + q], ww, a0);
      a1 = fmaf(cmb[w2*544 + (v+16) *17 + q], ww, a1);
    }
    float inv = 1.0f/L;
    int n = qb*16 + q;
    ATT[(size_t)n*256 + (size_t)(2*h  )*16 + v] = a0*inv;
    ATT[(size_t)n*256 + (size_t)(2*h+1)*16 + v] = a1*inv;
  }
}

__global__ __launch_bounds__(256) void reduce_kernel(const float* __restrict__ tok, float* __restrict__ out){
  int tid=threadIdx.x;
  float s=0;
  for(int i=tid;i<NTOK;i+=256) s+=tok[i];
#pragma unroll
  for(int off=32;off>0;off>>=1) s += __shfl_down(s,off);
  __shared__ float red[4];
  if((tid&63)==0) red[tid>>6]=s;
  __syncthreads();
  if(tid==0) out[0]=(red[0]+red[1]+red[2]+red[3])*(1.0f/2048.0f);
}

extern "C" void kernel_launch(void* const* d_in, const int* in_sizes, int n_in,
                              void* d_out, int out_size, void* d_ws, size_t ws_size,
                              hipStream_t stream){
  const float* points=(const float*)d_in[0];
  const float* Win=(const float*)d_in[1];
  const float* Wq=(const float*)d_in[2];
  const float* Wk=(const float*)d_in[3];
  const float* Wv=(const float*)d_in[4];
  const float* Wo=(const float*)d_in[5];
  const float* Wl=(const float*)d_in[6];
  const float* Wr=(const float*)d_in[7];
  const float* Wm=(const float*)d_in[8];
  const float* Wout=(const float*)d_in[9];
  float* ws=(float*)d_ws;
  float* X    = ws;                                         // 524288 f
  float* ATT  = ws + 524288;                                // 524288 f
  unsigned short* Qg16 = (unsigned short*)(ws + 1048576);   // 262144 us
  unsigned short* Kg16 = (unsigned short*)(ws + 1179648);   // 262144 us
  unsigned short* VgT  = (unsigned short*)(ws + 1310720);   // 524288 us
  float* tok  = ws + 1572864;
  float* out=(float*)d_out;

  token_kernel<0><<<256,128,0,stream>>>(points,Win,nullptr,nullptr,nullptr,nullptr,
                                        Wq,Wk,Wv,nullptr,nullptr,X,Qg16,Kg16,VgT,nullptr);
  for(int l=0;l<10;++l){
    attn_kernel<<<1024,256,0,stream>>>(Qg16,Kg16,VgT,ATT);
    if(l<9){
      token_kernel<1><<<256,128,0,stream>>>(nullptr,nullptr,
          Wo+l*2304,Wl+l*2304,Wr+l*2304,Wm+l*2304,
          Wq+(l+1)*2304,Wk+(l+1)*2304,Wv+(l+1)*2304,nullptr,
          ATT,X,Qg16,Kg16,VgT,nullptr);
    } else {
      token_kernel<2><<<256,128,0,stream>>>(nullptr,nullptr,
          Wo+l*2304,Wl+l*2304,Wr+l*2304,Wm+l*2304,
          nullptr,nullptr,nullptr,Wout,
          ATT,X,nullptr,nullptr,nullptr,tok);
    }
  }
  reduce_kernel<<<1,256,0,stream>>>(tok,out);
}